// Round 8
// baseline (477.652 us; speedup 1.0000x reference)
//
#include <hip/hip_runtime.h>

typedef unsigned short u16;
typedef unsigned int u32;
typedef __attribute__((ext_vector_type(8))) short short8;
typedef __attribute__((ext_vector_type(16))) float f32x16;

__device__ __forceinline__ u16 f2bf(float f) {
    u32 u = __float_as_uint(f);
    return (u16)((u + 0x7FFFu + ((u >> 16) & 1u)) >> 16);
}

#define COMP(f4, e) ((e) == 0 ? (f4).x : (e) == 1 ? (f4).y : (e) == 2 ? (f4).z : (f4).w)

// async global->LDS, 16B per lane. LDS dest is wave-uniform base (+lane*16 implicit).
__device__ __forceinline__ void gld16(const u16* g, u16* l) {
    __builtin_amdgcn_global_load_lds(
        (const __attribute__((address_space(1))) unsigned int*)(unsigned long long)(const void*)g,
        (__attribute__((address_space(3))) unsigned int*)(unsigned long long)(void*)l,
        16, 0, 0);
}

// ---------------------------------------------------------------------------
// Kernel 0a: NCHW fp32 -> halo-padded NHWC bf16 (unchanged).
// ---------------------------------------------------------------------------
__global__ __launch_bounds__(256) void nchw2nhwc_pad(const float* __restrict__ x,
                                                     u16* __restrict__ xp) {
    __shared__ __align__(16) u16 T[64][264];
    const int tid = threadIdx.x;
    const int b   = blockIdx.x;
    const int n   = b >> 6;
    const int row = b & 63;
    const int g16 = tid >> 4;
    const int pxq = tid & 15;

    const float* src = x + ((size_t)n * 256 + g16 * 16) * 4096 + row * 64 + pxq * 4;
    float4 v[4][4];
#pragma unroll
    for (int u = 0; u < 4; ++u)
#pragma unroll
        for (int i = 0; i < 4; ++i)
            v[u][i] = *(const float4*)(src + (size_t)(u * 4 + i) * 4096);

#pragma unroll
    for (int u = 0; u < 4; ++u) {
        const int ic = g16 * 16 + u * 4;
#pragma unroll
        for (int e = 0; e < 4; ++e) {
            const int px = pxq * 4 + e;
            const u32 lo = ((u32)f2bf(COMP(v[u][1], e)) << 16) | f2bf(COMP(v[u][0], e));
            const u32 hi = ((u32)f2bf(COMP(v[u][3], e)) << 16) | f2bf(COMP(v[u][2], e));
            *(uint2*)&T[px][ic] = make_uint2(lo, hi);
        }
    }
    __syncthreads();

    const int c = tid & 31, p0 = tid >> 5;
    u16* dstN = xp + ((size_t)n * 4356 + (size_t)(row + 1) * 66 + 1) * 256 + c * 8;
#pragma unroll
    for (int pp = 0; pp < 8; ++pp) {
        const int px = pp * 8 + p0;
        *(uint4*)(dstN + (size_t)px * 256) = *(const uint4*)&T[px][c * 8];
    }

    u16* hrow = xp + ((size_t)n * 4356 + (size_t)(row + 1) * 66) * 256;
    if (tid < 64) {
        const int wp = (tid >> 5) ? 65 : 0;
        uint4 zz = {0u, 0u, 0u, 0u};
        *(uint4*)(hrow + (size_t)wp * 256 + (tid & 31) * 8) = zz;
    }
    if (row == 0) {
        u16* tb = xp + (size_t)n * 4356 * 256;
        uint4 zz = {0u, 0u, 0u, 0u};
        for (int i = tid; i < 2112; i += 256) *(uint4*)(tb + (size_t)i * 8) = zz;
    }
    if (row == 63) {
        u16* bb = xp + ((size_t)n * 4356 + 65 * 66) * 256;
        uint4 zz = {0u, 0u, 0u, 0u};
        for (int i = tid; i < 2112; i += 256) *(uint4*)(bb + (size_t)i * 8) = zz;
    }
}

// ---------------------------------------------------------------------------
// Kernel 0b: hypernet weight generation, LDS-resident (unchanged).
// ---------------------------------------------------------------------------
__global__ __launch_bounds__(256) void wgen(const float* __restrict__ z,
                                            const float* __restrict__ W1,
                                            const float* __restrict__ B1,
                                            const float* __restrict__ W2,
                                            const float* __restrict__ B2,
                                            u16* __restrict__ wb) {
    __shared__ float zl[64][65];
    __shared__ float w1s[4096];
    __shared__ float aS[64][65];
    __shared__ float w2s[9216];

    const int tid = threadIdx.x;
    const int b   = blockIdx.x >> 2;
    const int lc  = blockIdx.x & 3;
    const int l   = tid & 63;
    const int g   = tid >> 6;

    const float* zg  = z  + (size_t)lc * 4096;
    const float* w1g = W1 + (size_t)b * 4096;
    const float* w2g = W2 + (size_t)b * 9216;
#pragma unroll
    for (int k = 0; k < 4; ++k) {
        const int i4 = tid + k * 256;
        const float4 v = *(const float4*)(zg + (size_t)i4 * 4);
        const int lr = i4 >> 4, nr = (i4 * 4) & 63;
        zl[lr][nr] = v.x; zl[lr][nr + 1] = v.y; zl[lr][nr + 2] = v.z; zl[lr][nr + 3] = v.w;
        *(float4*)(w1s + (size_t)i4 * 4) = *(const float4*)(w1g + (size_t)i4 * 4);
    }
#pragma unroll
    for (int k = 0; k < 9; ++k) {
        const int i4 = tid + k * 256;
        *(float4*)(w2s + (size_t)i4 * 4) = *(const float4*)(w2g + (size_t)i4 * 4);
    }
    __syncthreads();

    {
        float acc[16];
#pragma unroll
        for (int j = 0; j < 16; ++j) acc[j] = B1[b * 64 + g * 16 + j];
#pragma unroll
        for (int nb = 0; nb < 16; ++nb) {
            float zv0 = zl[l][nb * 4 + 0];
            float zv1 = zl[l][nb * 4 + 1];
            float zv2 = zl[l][nb * 4 + 2];
            float zv3 = zl[l][nb * 4 + 3];
#pragma unroll
            for (int j = 0; j < 16; ++j) {
                const float4 w = *(const float4*)(w1s + (g * 16 + j) * 64 + nb * 4);
                acc[j] += w.x * zv0 + w.y * zv1 + w.z * zv2 + w.w * zv3;
            }
        }
#pragma unroll
        for (int j = 0; j < 16; ++j) aS[l][g * 16 + j] = acc[j];
    }
    __syncthreads();

    float acc2[36];
#pragma unroll
    for (int t = 0; t < 36; ++t) acc2[t] = B2[b * 144 + g * 36 + t];
#pragma unroll
    for (int db = 0; db < 16; ++db) {
        float av0 = aS[l][db * 4 + 0];
        float av1 = aS[l][db * 4 + 1];
        float av2 = aS[l][db * 4 + 2];
        float av3 = aS[l][db * 4 + 3];
#pragma unroll
        for (int t = 0; t < 36; ++t) {
            const float4 w = *(const float4*)(w2s + (g * 36 + t) * 64 + db * 4);
            acc2[t] += w.x * av0 + w.y * av1 + w.z * av2 + w.w * av3;
        }
    }

    const int lg = lc * 64 + l;
    const int ob = lg >> 4, ib = lg & 15;
#pragma unroll
    for (int t = 0; t < 36; ++t) {
        const int b2 = 4 * g + t / 9;
        const int tap = t % 9;
        wb[(size_t)(ob * 16 + b2) * 2304 + tap * 256 + ib * 16 + b] = f2bf(acc2[t]);
    }
}

// ---------------------------------------------------------------------------
// Kernel 1: implicit-GEMM conv — r4 pipeline skeleton (4-slot circular LDS,
// 3-deep prefetch, counted vmcnt never 0 in steady state, 1 barrier/tile,
// involution swizzle) re-based on 4 waves x 128x128 per-wave tiles with
// mfma_f32_32x32x16_bf16:
//   - LDS reads/tile: 64 x b128 (vs 96) — reads/FLOP cut 33%
//   - MFMA on the faster 32x32 pipe (2495 vs 2075 TF ubench)
//   - acc = 4x4 f32x16 = 256 regs/lane -> 1 wave/SIMD; overlap comes from
//     within-wave lgkmcnt interleave of 16 reads among 32 MFMAs.
// Staging: 256 threads x (4 A + 4 B) gld16; linear LDS dest, per-lane
// pre-swizzled global source; swb=(lane&7)^(lane>>3) is lane-constant.
// phys cell (prow, ps): logical row=2*prow+par, (par<<2|kc)=ps^(prow&7).
// C/D layout (m74/m101): col=lane&31 (px), row=(reg&3)+8*(reg>>2)+4*(lane>>5).
// ---------------------------------------------------------------------------
__global__ __launch_bounds__(256, 1) void conv_mfma(const u16* __restrict__ xp,
                                                    const u16* __restrict__ wb,
                                                    float* __restrict__ out) {
    __shared__ __align__(16) u16 As[4][8192];   // 4 slots x 16 KB  (256 oc x 32 k)
    __shared__ __align__(16) u16 Bs[4][8192];   // 4 slots x 16 KB  (256 px x 32 k)

    const int tid  = threadIdx.x;
    const int b0   = blockIdx.x;
    const int bid  = (b0 & 7) * 64 + (b0 >> 3);   // XCD-chunked, 512 % 8 == 0
    const int n    = bid >> 4;                    // image
    const int pimg = (bid & 15) << 8;             // 256 px = 4 image rows
    const int lane = tid & 63;
    const int wave = tid >> 6;                    // 0..3
    const int wm2  = wave >> 1;                   // oc half
    const int wn2  = wave & 1;                    // px half
    const int l31  = lane & 31, l5 = lane >> 5;

    // ---- staging: lane-constant inverse swizzle ----
    const int swb    = (lane & 7) ^ (lane >> 3);  // = ps ^ (prow&7)
    const int par    = swb >> 2;
    const int kc     = swb & 3;                   // 16B k-chunk index (0..3)
    const int rowoff = 2 * (lane >> 3) + par;     // in [0,16)
    // A source: oc = q*64 + wave*16 + rowoff
    const u16* aBase = wb + (size_t)(wave * 16 + rowoff) * 2304 + kc * 8;
    // B source: px = q*64 + wave*16 + rowoff  ->  padded pixel index
    const int prow_img0 = (bid & 15) * 4;
    int pbq[4];
#pragma unroll
    for (int q = 0; q < 4; ++q)
        pbq[q] = (prow_img0 + 1 + q) * 66 + wave * 16 + rowoff + 1;
    const u16* xpN = xp + (size_t)n * 4356 * 256 + kc * 8;
    const int ldw = wave * 512;                   // u16: wave's 1KB segment base

    // ---- compute-side read constants ----
    const int prA  = wm2 * 64 + (l31 >> 1);       // + i*16 per frag
    const int prB  = wn2 * 64 + (l31 >> 1);
    const int psx  = (((l31 & 1) << 2)) ^ 0;      // parity bits (kc added per ks)
    const int pr7  = (l31 >> 1) & 7;
    const int psk0 = (((l31 & 1) << 2) | (0 + l5)) ^ pr7;   // ks=0: kc=l5
    const int psk1 = (((l31 & 1) << 2) | (2 + l5)) ^ pr7;   // ks=1: kc=2+l5
    (void)psx;

    f32x16 acc[4][4];
#pragma unroll
    for (int i = 0; i < 4; ++i)
#pragma unroll
        for (int j = 0; j < 4; ++j)
#pragma unroll
            for (int r = 0; r < 16; ++r) acc[i][j][r] = 0.f;

    // stage tile t into slot t&3: 4 A-gld16 + 4 B-gld16 per thread
    auto stage = [&](int t) {
        const int s = t & 3;
        const int tap = t >> 3, icb = t & 7;
        const int t3 = tap / 3;
        const int ko = tap * 256 + icb * 32;
        const int bo = ((t3 - 1) * 66 + (tap - t3 * 3 - 1)) * 256 + icb * 32;
        const u16* aS_ = aBase + ko;
#pragma unroll
        for (int q = 0; q < 4; ++q)
            gld16(aS_ + (size_t)q * 64 * 2304, &As[s][q * 2048 + ldw]);
        const u16* bS_ = xpN + bo;
#pragma unroll
        for (int q = 0; q < 4; ++q)
            gld16(bS_ + (size_t)pbq[q] * 256, &Bs[s][q * 2048 + ldw]);
    };

    auto compute = [&](int t) {
        const int s = t & 3;
        const u16* Ab = &As[s][0];
        const u16* Bb = &Bs[s][0];
#pragma unroll
        for (int ks = 0; ks < 2; ++ks) {
            const int ps = ks ? psk1 : psk0;
            short8 afr[4], bfr[4];
#pragma unroll
            for (int i = 0; i < 4; ++i)
                afr[i] = *(const short8*)(Ab + (prA + i * 16) * 64 + ps * 8);
#pragma unroll
            for (int j = 0; j < 4; ++j)
                bfr[j] = *(const short8*)(Bb + (prB + j * 16) * 64 + ps * 8);
            __builtin_amdgcn_s_setprio(1);
#pragma unroll
            for (int i = 0; i < 4; ++i)
#pragma unroll
                for (int j = 0; j < 4; ++j)
                    acc[i][j] = __builtin_amdgcn_mfma_f32_32x32x16_bf16(
                        afr[i], bfr[j], acc[i][j], 0, 0, 0);
            __builtin_amdgcn_s_setprio(0);
        }
    };

    // prologue: 3 tiles in flight (24 loads)
    stage(0); stage(1); stage(2);

#pragma unroll 1
    for (int t = 0; t < 72; ++t) {
        if (t < 70)       asm volatile("s_waitcnt vmcnt(16)" ::: "memory");
        else if (t == 70) asm volatile("s_waitcnt vmcnt(8)" ::: "memory");
        else              asm volatile("s_waitcnt vmcnt(0)" ::: "memory");
        __builtin_amdgcn_s_barrier();
        asm volatile("" ::: "memory");
        compute(t);
        if (t < 69) stage(t + 3);
    }

    // epilogue: C/D col=lane&31 (px), row=(reg&3)+8*(reg>>2)+4*l5 (oc)
    const size_t outn = (size_t)n * 256 * 4096;
    const int px0  = pimg + wn2 * 128 + l31;
    const int oc00 = wm2 * 128 + 4 * l5;
#pragma unroll
    for (int i = 0; i < 4; ++i) {
#pragma unroll
        for (int j = 0; j < 4; ++j) {
            float* op = out + outn + px0 + j * 32;
#pragma unroll
            for (int rg = 0; rg < 16; ++rg) {
                const int oc = oc00 + i * 32 + (rg & 3) + 8 * (rg >> 2);
                op[(size_t)oc * 4096] = acc[i][j][rg];
            }
        }
    }
}

extern "C" void kernel_launch(void* const* d_in, const int* in_sizes, int n_in,
                              void* d_out, int out_size, void* d_ws, size_t ws_size,
                              hipStream_t stream) {
    const float* x  = (const float*)d_in[0];
    const float* z  = (const float*)d_in[1];
    const float* W1 = (const float*)d_in[2];
    const float* B1 = (const float*)d_in[3];
    const float* W2 = (const float*)d_in[4];
    const float* B2 = (const float*)d_in[5];
    float* out = (float*)d_out;

    u16* xp = (u16*)d_ws;
    u16* wb = xp + (size_t)32 * 4356 * 256;
    const size_t need = ((size_t)32 * 4356 * 256 + (size_t)256 * 2304) * 2;
    if (ws_size < need) return;

    nchw2nhwc_pad<<<dim3(2048), dim3(256), 0, stream>>>(x, xp);
    wgen<<<dim3(64), dim3(256), 0, stream>>>(z, W1, B1, W2, B2, wb);
    conv_mfma<<<dim3(512), dim3(256), 0, stream>>>(xp, wb, out);
}